// Round 7
// baseline (1266.450 us; speedup 1.0000x reference)
//
#include <hip/hip_runtime.h>
#include <hip/hip_bf16.h>

#define N_NODES 100000
#define N_EDGES 3200000
#define F_IN    512
#define H_DIM   64
#define C_DIM   64
#define K_STEPS 10
#define ALPHA   0.1f
#define RSTRIDE 96   // max in-degree slot count (Poisson λ=32; P(deg>=96) ~ 4e-20/node)

typedef __attribute__((ext_vector_type(8))) short bf16x8;
typedef __attribute__((ext_vector_type(4))) float f32x4;

// ---- bf16 helpers (storage only; all math fp32) ----
__device__ __forceinline__ float bf2f(ushort u) {
    union { unsigned int i; float f; } c; c.i = ((unsigned int)u) << 16; return c.f;
}
__device__ __forceinline__ ushort f2bf(float f) {
    union { float f; unsigned int i; } c; c.f = f;
    unsigned int lsb = (c.i >> 16) & 1u;
    unsigned int r = c.i + 0x7fffu + lsb;   // round to nearest even
    return (ushort)(r >> 16);
}

// ---------------------------------------------------------------- single-pass CSR build
// slot-stride CSR: row d lives at esrc[d*RSTRIDE .. d*RSTRIDE+deg[d])
__global__ void build_kernel(const int* __restrict__ src, const int* __restrict__ dst,
                             int* __restrict__ deg, int* __restrict__ esrc, int e) {
    int i = blockIdx.x * blockDim.x + threadIdx.x;
    if (i >= e) return;
    int s = __builtin_nontemporal_load(&src[i]);
    int d = __builtin_nontemporal_load(&dst[i]);
    int pos = atomicAdd(&deg[d], 1);
    if (pos < RSTRIDE)
        __builtin_nontemporal_store(s, &esrc[d * RSTRIDE + pos]);
}

// ---------------------------------------------------------------- dinv + selfc
__global__ void dinv_kernel(const int* __restrict__ deg, float* __restrict__ dinv,
                            float* __restrict__ selfc, int n) {
    int i = blockIdx.x * blockDim.x + threadIdx.x;
    if (i < n) {
        float d = rsqrtf((float)deg[i] + 1.0f);
        dinv[i]  = d;
        selfc[i] = (1.0f - ALPHA) * d * d;
    }
}

// ---------------------------------------------------------------- convert weights to bf16
__global__ void cvt_w_kernel(const float* __restrict__ W1, const float* __restrict__ W2,
                             ushort* __restrict__ w1bf, ushort* __restrict__ w2bf) {
    int i = blockIdx.x * blockDim.x + threadIdx.x;
    if (i < 64 * 512) w1bf[i] = f2bf(W1[i]);
    if (i < 64 * 64)  w2bf[i] = f2bf(W2[i]);
}

// ---------------------------------------------------------------- fused MFMA MLP -> y0 = dinv*h, g = alpha*dinv*h
__global__ __launch_bounds__(256, 2) void mlp_mfma_kernel(
    const float* __restrict__ x, const ushort* __restrict__ w1bf, const float* __restrict__ b1,
    const ushort* __restrict__ w2bf, const float* __restrict__ b2, const float* __restrict__ dinv,
    ushort* __restrict__ y0, ushort* __restrict__ g, int n)
{
    __shared__ ushort w1s[64 * 512];
    __shared__ ushort w2s[64 * 64];
    __shared__ float  b1s[64], b2s[64];

    int t = threadIdx.x;
    #pragma unroll
    for (int i = 0; i < 16; ++i) {
        int chunk = i * 256 + t;
        int byte = chunk * 16;
        int row = byte >> 10;
        int dst = byte ^ ((row & 7) << 4);
        *reinterpret_cast<uint4*>((char*)w1s + dst) = reinterpret_cast<const uint4*>(w1bf)[chunk];
    }
    #pragma unroll
    for (int i = 0; i < 2; ++i) {
        int chunk = i * 256 + t;
        int byte = chunk * 16;
        int row = byte >> 7;
        int dst = byte ^ ((row & 7) << 4);
        *reinterpret_cast<uint4*>((char*)w2s + dst) = reinterpret_cast<const uint4*>(w2bf)[chunk];
    }
    if (t < 64) { b1s[t] = b1[t]; b2s[t] = b2[t]; }
    __syncthreads();

    int wid = t >> 6;
    int l   = t & 63;
    int lr  = l & 15;
    int lk  = l >> 4;
    int rowbase = blockIdx.x * 256 + wid * 64;

    f32x4 acc[4][4] = {};
    for (int kk = 0; kk < 16; ++kk) {
        int k0 = kk * 32 + lk * 8;
        bf16x8 a[4];
        #pragma unroll
        for (int fr = 0; fr < 4; ++fr) {
            int row = rowbase + fr * 16 + lr;
            row = (row < n) ? row : (n - 1);
            const float* p = x + (size_t)row * F_IN + k0;
            float4 u0 = *reinterpret_cast<const float4*>(p);
            float4 u1 = *reinterpret_cast<const float4*>(p + 4);
            bf16x8 af;
            af[0] = (short)f2bf(u0.x); af[1] = (short)f2bf(u0.y);
            af[2] = (short)f2bf(u0.z); af[3] = (short)f2bf(u0.w);
            af[4] = (short)f2bf(u1.x); af[5] = (short)f2bf(u1.y);
            af[6] = (short)f2bf(u1.z); af[7] = (short)f2bf(u1.w);
            a[fr] = af;
        }
        bf16x8 b[4];
        #pragma unroll
        for (int fc = 0; fc < 4; ++fc) {
            int nn = fc * 16 + lr;
            int byte = nn * 1024 + k0 * 2;
            b[fc] = *reinterpret_cast<const bf16x8*>((char*)w1s + (byte ^ ((nn & 7) << 4)));
        }
        #pragma unroll
        for (int fr = 0; fr < 4; ++fr)
            #pragma unroll
            for (int fc = 0; fc < 4; ++fc)
                acc[fr][fc] = __builtin_amdgcn_mfma_f32_16x16x32_bf16(a[fr], b[fc], acc[fr][fc], 0, 0, 0);
    }

    __syncthreads();
    ushort* h1w = w1s + wid * 4096;
    #pragma unroll
    for (int fr = 0; fr < 4; ++fr) {
        #pragma unroll
        for (int fc = 0; fc < 4; ++fc) {
            #pragma unroll
            for (int reg = 0; reg < 4; ++reg) {
                float v = acc[fr][fc][reg] + b1s[fc * 16 + lr];
                v = fmaxf(v, 0.f);
                int row = fr * 16 + lk * 4 + reg;
                int col = fc * 16 + lr;
                int byte = row * 128 + col * 2;
                *reinterpret_cast<ushort*>((char*)h1w + (byte ^ ((row & 7) << 4))) = f2bf(v);
            }
        }
    }

    f32x4 acc2[4][4] = {};
    #pragma unroll
    for (int kk = 0; kk < 2; ++kk) {
        int k0 = kk * 32 + lk * 8;
        bf16x8 a2[4], bb[4];
        #pragma unroll
        for (int fr = 0; fr < 4; ++fr) {
            int row = fr * 16 + lr;
            int byte = row * 128 + k0 * 2;
            a2[fr] = *reinterpret_cast<const bf16x8*>((char*)h1w + (byte ^ ((row & 7) << 4)));
        }
        #pragma unroll
        for (int fc = 0; fc < 4; ++fc) {
            int nn = fc * 16 + lr;
            int byte = nn * 128 + k0 * 2;
            bb[fc] = *reinterpret_cast<const bf16x8*>((char*)w2s + (byte ^ ((nn & 7) << 4)));
        }
        #pragma unroll
        for (int fr = 0; fr < 4; ++fr)
            #pragma unroll
            for (int fc = 0; fc < 4; ++fc)
                acc2[fr][fc] = __builtin_amdgcn_mfma_f32_16x16x32_bf16(a2[fr], bb[fc], acc2[fr][fc], 0, 0, 0);
    }

    #pragma unroll
    for (int fr = 0; fr < 4; ++fr) {
        #pragma unroll
        for (int fc = 0; fc < 4; ++fc) {
            #pragma unroll
            for (int reg = 0; reg < 4; ++reg) {
                int row = rowbase + fr * 16 + lk * 4 + reg;
                int col = fc * 16 + lr;
                if (row < n) {
                    float d = dinv[row];
                    float hv = (acc2[fr][fc][reg] + b2s[col]) * d;
                    size_t o = (size_t)row * 64 + col;
                    y0[o] = f2bf(hv);
                    g[o]  = f2bf(ALPHA * hv);
                }
            }
        }
    }
}

// ---------------------------------------------------------------- APPNP step
// wave = 1 node; lanes = 2 edges x 32 channel-pairs (uint = 2 bf16).
// y' = selfc*(sum_src y[src] + y) + g ;  LAST: fused log_softmax of z = y'/dinv
template<bool LAST>
__global__ __launch_bounds__(256) void appnp_step_kernel(
    const int* __restrict__ deg, const int* __restrict__ esrc,
    const float* __restrict__ selfc, const float* __restrict__ dinv,
    const ushort* __restrict__ yin, const ushort* __restrict__ g,
    ushort* __restrict__ yout, float* __restrict__ lsm, int n)
{
    int idx = blockIdx.x * blockDim.x + threadIdx.x;
    int wid = idx >> 6;
    if (wid >= n) return;
    int lane = threadIdx.x & 63;
    int half = lane >> 5;      // which of 2 concurrent edges
    int ch2 = lane & 31;       // channel-pair (2 bf16 per uint)
    const uint* y32 = (const uint*)yin;
    int cnt = deg[wid];
    cnt = (cnt < RSTRIDE) ? cnt : RSTRIDE;
    int base = wid * RSTRIDE;

    float f0 = 0.f, f1 = 0.f, f2 = 0.f, f3 = 0.f;
    float f4 = 0.f, f5 = 0.f, f6 = 0.f, f7 = 0.f;
    int e = 0;
    for (; e + 7 < cnt; e += 8) {
        int s0 = __builtin_nontemporal_load(&esrc[base + e + half]);
        int s1 = __builtin_nontemporal_load(&esrc[base + e + 2 + half]);
        int s2 = __builtin_nontemporal_load(&esrc[base + e + 4 + half]);
        int s3 = __builtin_nontemporal_load(&esrc[base + e + 6 + half]);
        uint v0 = y32[(size_t)s0 * 32 + ch2];
        uint v1 = y32[(size_t)s1 * 32 + ch2];
        uint v2 = y32[(size_t)s2 * 32 + ch2];
        uint v3 = y32[(size_t)s3 * 32 + ch2];
        f0 += bf2f((ushort)v0); f1 += bf2f((ushort)(v0 >> 16));
        f2 += bf2f((ushort)v1); f3 += bf2f((ushort)(v1 >> 16));
        f4 += bf2f((ushort)v2); f5 += bf2f((ushort)(v2 >> 16));
        f6 += bf2f((ushort)v3); f7 += bf2f((ushort)(v3 >> 16));
    }
    for (; e < cnt; e += 2) {
        bool valid = (e + half) < cnt;
        int s = __builtin_nontemporal_load(&esrc[valid ? (base + e + half) : base]);
        uint v = y32[(size_t)s * 32 + ch2];
        f0 += valid ? bf2f((ushort)v) : 0.f;
        f1 += valid ? bf2f((ushort)(v >> 16)) : 0.f;
    }
    float se = (f0 + f2) + (f4 + f6);   // even channel
    float so = (f1 + f3) + (f5 + f7);   // odd channel
    se += __shfl_xor(se, 32);
    so += __shfl_xor(so, 32);

    size_t o32 = (size_t)wid * 32 + ch2;
    uint ys = y32[o32];
    uint gg = ((const uint*)g)[o32];
    float sc = selfc[wid];
    float yn0 = sc * (se + bf2f((ushort)ys)) + bf2f((ushort)gg);
    float yn1 = sc * (so + bf2f((ushort)(ys >> 16))) + bf2f((ushort)(gg >> 16));

    if (!LAST) {
        if (half == 0) {
            uint packed = (uint)f2bf(yn0) | ((uint)f2bf(yn1) << 16);
            ((uint*)yout)[o32] = packed;
        }
    } else {
        float di = dinv[wid];
        float z0 = yn0 / di, z1 = yn1 / di;
        float m = fmaxf(z0, z1);
        #pragma unroll
        for (int off = 16; off > 0; off >>= 1) m = fmaxf(m, __shfl_xor(m, off));
        float s = expf(z0 - m) + expf(z1 - m);
        #pragma unroll
        for (int off = 16; off > 0; off >>= 1) s += __shfl_xor(s, off);
        float ls = logf(s);
        if (half == 0) {
            float2 w = make_float2(z0 - m - ls, z1 - m - ls);
            *reinterpret_cast<float2*>(&lsm[(size_t)wid * 64 + 2 * ch2]) = w;
        }
    }
}

// ---------------------------------------------------------------- launch
extern "C" void kernel_launch(void* const* d_in, const int* in_sizes, int n_in,
                              void* d_out, int out_size, void* d_ws, size_t ws_size,
                              hipStream_t stream) {
    const float* x  = (const float*)d_in[0];
    const float* W1 = (const float*)d_in[1];
    const float* b1 = (const float*)d_in[2];
    const float* W2 = (const float*)d_in[3];
    const float* b2 = (const float*)d_in[4];
    const int*   ei = (const int*)d_in[5];
    const int* src = ei;
    const int* dst = ei + N_EDGES;
    float* out = (float*)d_out;

    char* ws = (char*)d_ws;
    size_t off = 0;
    auto alloc = [&](size_t bytes) -> void* {
        void* p = ws + off;
        off += (bytes + 255) & ~(size_t)255;
        return p;
    };
    int*    deg   = (int*)   alloc((size_t)N_NODES * 4);
    float*  dinv  = (float*) alloc((size_t)N_NODES * 4);
    float*  selfc = (float*) alloc((size_t)N_NODES * 4);
    int*    esrc  = (int*)   alloc((size_t)N_NODES * RSTRIDE * 4);   // 38.4 MB
    ushort* g     = (ushort*)alloc((size_t)N_NODES * 64 * 2);
    ushort* ya    = (ushort*)alloc((size_t)N_NODES * 64 * 2);
    ushort* yb    = (ushort*)alloc((size_t)N_NODES * 64 * 2);
    ushort* w1bf  = (ushort*)alloc((size_t)H_DIM * F_IN * 2);
    ushort* w2bf  = (ushort*)alloc((size_t)C_DIM * H_DIM * 2);

    hipMemsetAsync(deg, 0, (size_t)N_NODES * 4, stream);
    build_kernel<<<(N_EDGES + 255) / 256, 256, 0, stream>>>(src, dst, deg, esrc, N_EDGES);
    dinv_kernel<<<(N_NODES + 255) / 256, 256, 0, stream>>>(deg, dinv, selfc, N_NODES);
    cvt_w_kernel<<<(H_DIM * F_IN + 255) / 256, 256, 0, stream>>>(W1, W2, w1bf, w2bf);
    mlp_mfma_kernel<<<(N_NODES + 255) / 256, 256, 0, stream>>>(x, w1bf, b1, w2bf, b2, dinv,
                                                               ya, g, N_NODES);

    const int grid = (N_NODES * 64 + 255) / 256;
    ushort* yin = ya;
    ushort* yout = yb;
    for (int k = 0; k < K_STEPS - 1; ++k) {
        appnp_step_kernel<false><<<grid, 256, 0, stream>>>(
            deg, esrc, selfc, dinv, yin, g, yout, nullptr, N_NODES);
        ushort* tmp = yin; yin = yout; yout = tmp;
    }
    appnp_step_kernel<true><<<grid, 256, 0, stream>>>(
        deg, esrc, selfc, dinv, yin, g, nullptr, out, N_NODES);
}

// Round 8
// 1150.505 us; speedup vs baseline: 1.1008x; 1.1008x over previous
//
#include <hip/hip_runtime.h>
#include <hip/hip_bf16.h>

#define N_NODES 100000
#define N_EDGES 3200000
#define F_IN    512
#define H_DIM   64
#define C_DIM   64
#define K_STEPS 10
#define ALPHA   0.1f
#define RSTRIDE 96      // max in-degree slots (Poisson λ=32; overflow P ~ 1e-20)
#define NBINS   256
#define BINW    391     // 256*391 = 100096 >= N_NODES
#define SLOTS   16384   // per-bin staging capacity (mean 12500, +35σ)

typedef __attribute__((ext_vector_type(8))) short bf16x8;
typedef __attribute__((ext_vector_type(4))) float f32x4;

// ---- bf16 helpers (storage only; all math fp32) ----
__device__ __forceinline__ float bf2f(ushort u) {
    union { unsigned int i; float f; } c; c.i = ((unsigned int)u) << 16; return c.f;
}
__device__ __forceinline__ ushort f2bf(float f) {
    union { float f; unsigned int i; } c; c.f = f;
    unsigned int lsb = (c.i >> 16) & 1u;
    unsigned int r = c.i + 0x7fffu + lsb;   // round to nearest even
    return (ushort)(r >> 16);
}

// ---------------------------------------------------------------- pass A: bin edges by dst range
// packed record: src (17b) | dst_local (9b) << 17
__global__ __launch_bounds__(256) void binA_kernel(
    const int* __restrict__ src, const int* __restrict__ dst,
    int* __restrict__ gcursor, uint* __restrict__ staging, int e)
{
    __shared__ int cnt[NBINS];
    __shared__ int gbase[NBINS];
    __shared__ int loff[NBINS];
    int t = threadIdx.x;
    cnt[t] = 0;
    __syncthreads();

    int base = blockIdx.x * 4096;
    int  s[16];
    int  b[16];
    ushort dl[16];
    #pragma unroll
    for (int j = 0; j < 16; ++j) {
        int i = base + j * 256 + t;
        bool v = i < e;
        int ss = v ? __builtin_nontemporal_load(&src[i]) : -1;
        int dd = v ? __builtin_nontemporal_load(&dst[i]) : 0;
        int bb = dd / BINW;
        s[j] = ss; b[j] = bb; dl[j] = (ushort)(dd - bb * BINW);
        if (ss >= 0) atomicAdd(&cnt[bb], 1);
    }
    __syncthreads();
    int c = cnt[t];
    if (c > 0) gbase[t] = atomicAdd(&gcursor[t], c);
    loff[t] = 0;
    __syncthreads();
    #pragma unroll
    for (int j = 0; j < 16; ++j) {
        if (s[j] >= 0) {
            int lp = atomicAdd(&loff[b[j]], 1);
            int gp = gbase[b[j]] + lp;
            if (gp < SLOTS)
                __builtin_nontemporal_store(((uint)s[j]) | (((uint)dl[j]) << 17),
                                            &staging[(size_t)b[j] * SLOTS + gp]);
        }
    }
}

// ---------------------------------------------------------------- pass B: per-bin CSR fill (LDS counters)
__global__ __launch_bounds__(256) void binB_kernel(
    const int* __restrict__ gcursor, const uint* __restrict__ staging,
    int* __restrict__ deg, int* __restrict__ esrc, int n)
{
    __shared__ int dloc[BINW];
    int b = blockIdx.x, t = threadIdx.x;
    for (int i = t; i < BINW; i += 256) dloc[i] = 0;
    __syncthreads();

    int cnt = gcursor[b];
    cnt = (cnt < SLOTS) ? cnt : SLOTS;
    const uint* st = staging + (size_t)b * SLOTS;
    int nb = b * BINW;

    int j = t;
    for (; j + 768 < cnt; j += 1024) {
        uint p0 = st[j], p1 = st[j + 256], p2 = st[j + 512], p3 = st[j + 768];
        int d0 = p0 >> 17, d1 = p1 >> 17, d2 = p2 >> 17, d3 = p3 >> 17;
        int q0 = atomicAdd(&dloc[d0], 1);
        int q1 = atomicAdd(&dloc[d1], 1);
        int q2 = atomicAdd(&dloc[d2], 1);
        int q3 = atomicAdd(&dloc[d3], 1);
        if (q0 < RSTRIDE) esrc[(size_t)(nb + d0) * RSTRIDE + q0] = (int)(p0 & 0x1FFFFu);
        if (q1 < RSTRIDE) esrc[(size_t)(nb + d1) * RSTRIDE + q1] = (int)(p1 & 0x1FFFFu);
        if (q2 < RSTRIDE) esrc[(size_t)(nb + d2) * RSTRIDE + q2] = (int)(p2 & 0x1FFFFu);
        if (q3 < RSTRIDE) esrc[(size_t)(nb + d3) * RSTRIDE + q3] = (int)(p3 & 0x1FFFFu);
    }
    for (; j < cnt; j += 256) {
        uint p = st[j];
        int d = p >> 17;
        int q = atomicAdd(&dloc[d], 1);
        if (q < RSTRIDE) esrc[(size_t)(nb + d) * RSTRIDE + q] = (int)(p & 0x1FFFFu);
    }
    __syncthreads();
    for (int i = t; i < BINW; i += 256) {
        int node = nb + i;
        if (node < n) deg[node] = dloc[i];
    }
}

// ---------------------------------------------------------------- dinv + selfc
__global__ void dinv_kernel(const int* __restrict__ deg, float* __restrict__ dinv,
                            float* __restrict__ selfc, int n) {
    int i = blockIdx.x * blockDim.x + threadIdx.x;
    if (i < n) {
        float d = rsqrtf((float)deg[i] + 1.0f);
        dinv[i]  = d;
        selfc[i] = (1.0f - ALPHA) * d * d;
    }
}

// ---------------------------------------------------------------- convert weights to bf16
__global__ void cvt_w_kernel(const float* __restrict__ W1, const float* __restrict__ W2,
                             ushort* __restrict__ w1bf, ushort* __restrict__ w2bf) {
    int i = blockIdx.x * blockDim.x + threadIdx.x;
    if (i < 64 * 512) w1bf[i] = f2bf(W1[i]);
    if (i < 64 * 64)  w2bf[i] = f2bf(W2[i]);
}

// ---------------------------------------------------------------- fused MFMA MLP -> y0 = dinv*h, g = alpha*dinv*h
// W1 read direct from global (each wave reads it exactly once; L1/L2-served).
// LDS: per-wave h1 staging (32KB) + w2 (8KB). No mid-kernel barriers.
__global__ __launch_bounds__(256, 3) void mlp_mfma_kernel(
    const float* __restrict__ x, const ushort* __restrict__ w1bf, const float* __restrict__ b1,
    const ushort* __restrict__ w2bf, const float* __restrict__ b2, const float* __restrict__ dinv,
    ushort* __restrict__ y0, ushort* __restrict__ g, int n)
{
    __shared__ ushort h1s[4 * 4096];   // per-wave 64x64 bf16, swizzled
    __shared__ ushort w2s[64 * 64];    // swizzled: row = byte>>7
    __shared__ float  b1s[64], b2s[64];

    int t = threadIdx.x;
    #pragma unroll
    for (int i = 0; i < 2; ++i) {
        int chunk = i * 256 + t;
        int byte = chunk * 16;
        int row = byte >> 7;
        int dst = byte ^ ((row & 7) << 4);
        *reinterpret_cast<uint4*>((char*)w2s + dst) = reinterpret_cast<const uint4*>(w2bf)[chunk];
    }
    if (t < 64) { b1s[t] = b1[t]; b2s[t] = b2[t]; }
    __syncthreads();

    int wid = t >> 6;
    int l   = t & 63;
    int lr  = l & 15;
    int lk  = l >> 4;
    int rowbase = blockIdx.x * 256 + wid * 64;

    f32x4 acc[4][4] = {};
    for (int kk = 0; kk < 16; ++kk) {
        int k0 = kk * 32 + lk * 8;
        bf16x8 a[4];
        #pragma unroll
        for (int fr = 0; fr < 4; ++fr) {
            int row = rowbase + fr * 16 + lr;
            row = (row < n) ? row : (n - 1);
            const float* p = x + (size_t)row * F_IN + k0;
            f32x4 u0 = __builtin_nontemporal_load(reinterpret_cast<const f32x4*>(p));
            f32x4 u1 = __builtin_nontemporal_load(reinterpret_cast<const f32x4*>(p + 4));
            bf16x8 af;
            af[0] = (short)f2bf(u0[0]); af[1] = (short)f2bf(u0[1]);
            af[2] = (short)f2bf(u0[2]); af[3] = (short)f2bf(u0[3]);
            af[4] = (short)f2bf(u1[0]); af[5] = (short)f2bf(u1[1]);
            af[6] = (short)f2bf(u1[2]); af[7] = (short)f2bf(u1[3]);
            a[fr] = af;
        }
        bf16x8 b[4];
        #pragma unroll
        for (int fc = 0; fc < 4; ++fc) {
            int nn = fc * 16 + lr;
            b[fc] = *reinterpret_cast<const bf16x8*>(w1bf + (size_t)nn * F_IN + k0);
        }
        #pragma unroll
        for (int fr = 0; fr < 4; ++fr)
            #pragma unroll
            for (int fc = 0; fc < 4; ++fc)
                acc[fr][fc] = __builtin_amdgcn_mfma_f32_16x16x32_bf16(a[fr], b[fc], acc[fr][fc], 0, 0, 0);
    }

    // bias + relu -> per-wave LDS staging (swizzled)
    ushort* h1w = h1s + wid * 4096;
    #pragma unroll
    for (int fr = 0; fr < 4; ++fr) {
        #pragma unroll
        for (int fc = 0; fc < 4; ++fc) {
            #pragma unroll
            for (int reg = 0; reg < 4; ++reg) {
                float v = acc[fr][fc][reg] + b1s[fc * 16 + lr];
                v = fmaxf(v, 0.f);
                int row = fr * 16 + lk * 4 + reg;
                int col = fc * 16 + lr;
                int byte = row * 128 + col * 2;
                *reinterpret_cast<ushort*>((char*)h1w + (byte ^ ((row & 7) << 4))) = f2bf(v);
            }
        }
    }

    f32x4 acc2[4][4] = {};
    #pragma unroll
    for (int kk = 0; kk < 2; ++kk) {
        int k0 = kk * 32 + lk * 8;
        bf16x8 a2[4], bb[4];
        #pragma unroll
        for (int fr = 0; fr < 4; ++fr) {
            int row = fr * 16 + lr;
            int byte = row * 128 + k0 * 2;
            a2[fr] = *reinterpret_cast<const bf16x8*>((char*)h1w + (byte ^ ((row & 7) << 4)));
        }
        #pragma unroll
        for (int fc = 0; fc < 4; ++fc) {
            int nn = fc * 16 + lr;
            int byte = nn * 128 + k0 * 2;
            bb[fc] = *reinterpret_cast<const bf16x8*>((char*)w2s + (byte ^ ((nn & 7) << 4)));
        }
        #pragma unroll
        for (int fr = 0; fr < 4; ++fr)
            #pragma unroll
            for (int fc = 0; fc < 4; ++fc)
                acc2[fr][fc] = __builtin_amdgcn_mfma_f32_16x16x32_bf16(a2[fr], bb[fc], acc2[fr][fc], 0, 0, 0);
    }

    #pragma unroll
    for (int fr = 0; fr < 4; ++fr) {
        #pragma unroll
        for (int fc = 0; fc < 4; ++fc) {
            #pragma unroll
            for (int reg = 0; reg < 4; ++reg) {
                int row = rowbase + fr * 16 + lk * 4 + reg;
                int col = fc * 16 + lr;
                if (row < n) {
                    float d = dinv[row];
                    float hv = (acc2[fr][fc][reg] + b2s[col]) * d;
                    size_t o = (size_t)row * 64 + col;
                    y0[o] = f2bf(hv);
                    g[o]  = f2bf(ALPHA * hv);
                }
            }
        }
    }
}

// ---------------------------------------------------------------- APPNP step
// wave = 1 node; lanes = 2 edges x 32 channel-pairs (uint = 2 bf16).
// y' = selfc*(sum_src y[src] + y) + g ;  LAST: fused log_softmax of z = y'/dinv
template<bool LAST>
__global__ __launch_bounds__(256) void appnp_step_kernel(
    const int* __restrict__ deg, const int* __restrict__ esrc,
    const float* __restrict__ selfc, const float* __restrict__ dinv,
    const ushort* __restrict__ yin, const ushort* __restrict__ g,
    ushort* __restrict__ yout, float* __restrict__ lsm, int n)
{
    int idx = blockIdx.x * blockDim.x + threadIdx.x;
    int wid = idx >> 6;
    if (wid >= n) return;
    int lane = threadIdx.x & 63;
    int half = lane >> 5;      // which of 2 concurrent edges
    int ch2 = lane & 31;       // channel-pair (2 bf16 per uint)
    const uint* y32 = (const uint*)yin;
    int cnt = deg[wid];
    cnt = (cnt < RSTRIDE) ? cnt : RSTRIDE;
    int base = wid * RSTRIDE;

    float f0 = 0.f, f1 = 0.f, f2 = 0.f, f3 = 0.f;
    float f4 = 0.f, f5 = 0.f, f6 = 0.f, f7 = 0.f;
    int e = 0;
    for (; e + 7 < cnt; e += 8) {
        int s0 = __builtin_nontemporal_load(&esrc[base + e + half]);
        int s1 = __builtin_nontemporal_load(&esrc[base + e + 2 + half]);
        int s2 = __builtin_nontemporal_load(&esrc[base + e + 4 + half]);
        int s3 = __builtin_nontemporal_load(&esrc[base + e + 6 + half]);
        uint v0 = y32[(size_t)s0 * 32 + ch2];
        uint v1 = y32[(size_t)s1 * 32 + ch2];
        uint v2 = y32[(size_t)s2 * 32 + ch2];
        uint v3 = y32[(size_t)s3 * 32 + ch2];
        f0 += bf2f((ushort)v0); f1 += bf2f((ushort)(v0 >> 16));
        f2 += bf2f((ushort)v1); f3 += bf2f((ushort)(v1 >> 16));
        f4 += bf2f((ushort)v2); f5 += bf2f((ushort)(v2 >> 16));
        f6 += bf2f((ushort)v3); f7 += bf2f((ushort)(v3 >> 16));
    }
    for (; e < cnt; e += 2) {
        bool valid = (e + half) < cnt;
        int s = __builtin_nontemporal_load(&esrc[valid ? (base + e + half) : base]);
        uint v = y32[(size_t)s * 32 + ch2];
        f0 += valid ? bf2f((ushort)v) : 0.f;
        f1 += valid ? bf2f((ushort)(v >> 16)) : 0.f;
    }
    float se = (f0 + f2) + (f4 + f6);   // even channel
    float so = (f1 + f3) + (f5 + f7);   // odd channel
    se += __shfl_xor(se, 32);
    so += __shfl_xor(so, 32);

    size_t o32 = (size_t)wid * 32 + ch2;
    uint ys = y32[o32];
    uint gg = ((const uint*)g)[o32];
    float sc = selfc[wid];
    float yn0 = sc * (se + bf2f((ushort)ys)) + bf2f((ushort)gg);
    float yn1 = sc * (so + bf2f((ushort)(ys >> 16))) + bf2f((ushort)(gg >> 16));

    if (!LAST) {
        if (half == 0) {
            uint packed = (uint)f2bf(yn0) | ((uint)f2bf(yn1) << 16);
            ((uint*)yout)[o32] = packed;
        }
    } else {
        float di = dinv[wid];
        float z0 = yn0 / di, z1 = yn1 / di;
        float m = fmaxf(z0, z1);
        #pragma unroll
        for (int off = 16; off > 0; off >>= 1) m = fmaxf(m, __shfl_xor(m, off));
        float s = expf(z0 - m) + expf(z1 - m);
        #pragma unroll
        for (int off = 16; off > 0; off >>= 1) s += __shfl_xor(s, off);
        float ls = logf(s);
        if (half == 0) {
            float2 w = make_float2(z0 - m - ls, z1 - m - ls);
            *reinterpret_cast<float2*>(&lsm[(size_t)wid * 64 + 2 * ch2]) = w;
        }
    }
}

// ---------------------------------------------------------------- launch
extern "C" void kernel_launch(void* const* d_in, const int* in_sizes, int n_in,
                              void* d_out, int out_size, void* d_ws, size_t ws_size,
                              hipStream_t stream) {
    const float* x  = (const float*)d_in[0];
    const float* W1 = (const float*)d_in[1];
    const float* b1 = (const float*)d_in[2];
    const float* W2 = (const float*)d_in[3];
    const float* b2 = (const float*)d_in[4];
    const int*   ei = (const int*)d_in[5];
    const int* src = ei;
    const int* dst = ei + N_EDGES;
    float* out = (float*)d_out;

    char* ws = (char*)d_ws;
    size_t off = 0;
    auto alloc = [&](size_t bytes) -> void* {
        void* p = ws + off;
        off += (bytes + 255) & ~(size_t)255;
        return p;
    };
    int*    deg     = (int*)   alloc((size_t)N_NODES * 4);
    float*  dinv    = (float*) alloc((size_t)N_NODES * 4);
    float*  selfc   = (float*) alloc((size_t)N_NODES * 4);
    int*    gcursor = (int*)   alloc((size_t)NBINS * 4);
    uint*   staging = (uint*)  alloc((size_t)NBINS * SLOTS * 4);      // 16 MB
    int*    esrc    = (int*)   alloc((size_t)N_NODES * RSTRIDE * 4);  // 38.4 MB
    ushort* g       = (ushort*)alloc((size_t)N_NODES * 64 * 2);
    ushort* ya      = (ushort*)alloc((size_t)N_NODES * 64 * 2);
    ushort* yb      = (ushort*)alloc((size_t)N_NODES * 64 * 2);
    ushort* w1bf    = (ushort*)alloc((size_t)H_DIM * F_IN * 2);
    ushort* w2bf    = (ushort*)alloc((size_t)C_DIM * H_DIM * 2);

    hipMemsetAsync(gcursor, 0, (size_t)NBINS * 4, stream);
    binA_kernel<<<(N_EDGES + 4095) / 4096, 256, 0, stream>>>(src, dst, gcursor, staging, N_EDGES);
    binB_kernel<<<NBINS, 256, 0, stream>>>(gcursor, staging, deg, esrc, N_NODES);
    dinv_kernel<<<(N_NODES + 255) / 256, 256, 0, stream>>>(deg, dinv, selfc, N_NODES);
    cvt_w_kernel<<<(H_DIM * F_IN + 255) / 256, 256, 0, stream>>>(W1, W2, w1bf, w2bf);
    mlp_mfma_kernel<<<(N_NODES + 255) / 256, 256, 0, stream>>>(x, w1bf, b1, w2bf, b2, dinv,
                                                               ya, g, N_NODES);

    const int grid = (N_NODES * 64 + 255) / 256;
    ushort* yin = ya;
    ushort* yout = yb;
    for (int k = 0; k < K_STEPS - 1; ++k) {
        appnp_step_kernel<false><<<grid, 256, 0, stream>>>(
            deg, esrc, selfc, dinv, yin, g, yout, nullptr, N_NODES);
        ushort* tmp = yin; yin = yout; yout = tmp;
    }
    appnp_step_kernel<true><<<grid, 256, 0, stream>>>(
        deg, esrc, selfc, dinv, yin, g, nullptr, out, N_NODES);
}